// Round 5
// baseline (951.344 us; speedup 1.0000x reference)
//
#include <hip/hip_runtime.h>
#include <hip/hip_bf16.h>

// Problem constants
#define T_    1024
#define B_    4
#define D_    768
#define H_    12
#define HD_   64
#define FF_   3072

typedef __bf16 bf16;
typedef __bf16 v8bf __attribute__((ext_vector_type(8)));
typedef __bf16 v4bf __attribute__((ext_vector_type(4)));
typedef float  v4f  __attribute__((ext_vector_type(4)));

#define AS1 __attribute__((address_space(1)))
#define AS3 __attribute__((address_space(3)))
// async global->LDS, 16B per lane, deposit = wave-uniform base + lane*16
#define GLOAD_LDS(g, l) __builtin_amdgcn_global_load_lds((AS1 void*)(g), (AS3 void*)(l), 16, 0, 0)

static const float ALPHA_ = 2.2133638394006434f; // 24^0.25

#define MODE_PLAIN 0
#define MODE_GELU  1

// ---------------------------------------------------------------------------
// Fused fp32 -> bf16 cast for ALL tensors in one launch.
// Segment boundaries are compile-time and block-aligned (no divergence):
//   states 786432 f4 (3072 blk), Wq/Wk/Wv/Wo 147456 each (576 blk),
//   W1/W2 589824 each (2304 blk).  Total 2555904 f4 = 9984 blocks.
// ---------------------------------------------------------------------------
#define SEG0 786432            // states end
#define SEG1 (SEG0 + 147456)   // Wq end
#define SEG2 (SEG1 + 147456)   // Wk end
#define SEG3 (SEG2 + 147456)   // Wv end
#define SEG4 (SEG3 + 147456)   // Wo end
#define SEG5 (SEG4 + 589824)   // W1 end
#define SEG6 (SEG5 + 589824)   // W2 end (= 2555904)

__global__ __launch_bounds__(256) void cast_all(
    const float4* __restrict__ states, const float4* __restrict__ wq,
    const float4* __restrict__ wk, const float4* __restrict__ wv,
    const float4* __restrict__ wo, const float4* __restrict__ w1,
    const float4* __restrict__ w2,
    v4bf* __restrict__ o_states, v4bf* __restrict__ o_wq,
    v4bf* __restrict__ o_wk, v4bf* __restrict__ o_wv,
    v4bf* __restrict__ o_wo, v4bf* __restrict__ o_w1,
    v4bf* __restrict__ o_w2) {
  int i = blockIdx.x * 256 + threadIdx.x;
  const float4* src; v4bf* dst; int off;
  if      (i < SEG0) { src = states; dst = o_states; off = 0;    }
  else if (i < SEG1) { src = wq;     dst = o_wq;     off = SEG0; }
  else if (i < SEG2) { src = wk;     dst = o_wk;     off = SEG1; }
  else if (i < SEG3) { src = wv;     dst = o_wv;     off = SEG2; }
  else if (i < SEG4) { src = wo;     dst = o_wo;     off = SEG3; }
  else if (i < SEG5) { src = w1;     dst = o_w1;     off = SEG4; }
  else               { src = w2;     dst = o_w2;     off = SEG5; }
  float4 v = src[i - off];
  v4bf o;
  o[0] = (bf16)v.x; o[1] = (bf16)v.y; o[2] = (bf16)v.z; o[3] = (bf16)v.w;
  dst[i - off] = o;
}

// ---------------------------------------------------------------------------
// MFMA GEMM core: Out(128x128 tile) = X(N x K) @ W(M x K)^T over k in
// [kBeg, kEnd).  K is the row stride.
// LDS is stored in MFMA-fragment order: 8 blocks of 1024B per tile; block g
// holds rows 16g..16g+15; within a block, lane l's 16B chunk is exactly the
// fragment lane l reads (row = l&15, k-bytes = (l>>4)*16). So global_load_lds
// (wave-uniform base + lane*16) deposits fragments in place, and the compute
// ds_read_b128 at base + lane*16 is contiguous (conflict-free).
// 256 threads = 4 waves in a 2x2 grid, each wave owns a 64x64 sub-tile.
// ---------------------------------------------------------------------------
__device__ __forceinline__ void gemm_core(
    const bf16* __restrict__ X, const bf16* __restrict__ W, int K,
    int kBeg, int kEnd,
    int row0, int col0, bf16* As, bf16* Bs, v4f (&acc)[4][4]) {
  const int tid  = threadIdx.x;
  const int lane = tid & 63;
  const int w    = tid >> 6;        // wave 0..3
  const int wm   = w >> 1, wn = w & 1;
  const int lr   = lane & 15;       // row within 16-row group
  const int lq   = lane >> 4;       // k-quad 0..3 (8 bf16 = 16B each)

  const bf16* xg0 = X + (size_t)(row0 + 16 * w       + lr) * K + lq * 8;
  const bf16* xg1 = X + (size_t)(row0 + 16 * (w + 4) + lr) * K + lq * 8;
  const bf16* wg0 = W + (size_t)(col0 + 16 * w       + lr) * K + lq * 8;
  const bf16* wg1 = W + (size_t)(col0 + 16 * (w + 4) + lr) * K + lq * 8;
  char* AsB = (char*)As;
  char* BsB = (char*)Bs;

  for (int k0 = kBeg; k0 < kEnd; k0 += 32) {
    __syncthreads();
    GLOAD_LDS(xg0 + k0, AsB + w * 1024);
    GLOAD_LDS(xg1 + k0, AsB + (w + 4) * 1024);
    GLOAD_LDS(wg0 + k0, BsB + w * 1024);
    GLOAD_LDS(wg1 + k0, BsB + (w + 4) * 1024);
    __syncthreads();

    v8bf af[4], bw[4];
#pragma unroll
    for (int mi = 0; mi < 4; mi++)
      af[mi] = *(const v8bf*)(AsB + (wm * 4 + mi) * 1024 + lane * 16);
#pragma unroll
    for (int ni = 0; ni < 4; ni++)
      bw[ni] = *(const v8bf*)(BsB + (wn * 4 + ni) * 1024 + lane * 16);
#pragma unroll
    for (int mi = 0; mi < 4; mi++)
#pragma unroll
      for (int ni = 0; ni < 4; ni++)
        acc[mi][ni] = __builtin_amdgcn_mfma_f32_16x16x32_bf16(
            af[mi], bw[ni], acc[mi][ni], 0, 0, 0);
  }
}

// ---------------------------------------------------------------------------
// Generic MFMA GEMM: out = X @ W^T + bias, PLAIN(f32) or GELU(bf16) epilogue.
// Grid (M/128, N/128), 256 threads.
// ---------------------------------------------------------------------------
__global__ __launch_bounds__(256) void gemm_mfma(
    const bf16* __restrict__ X, const bf16* __restrict__ W,
    const float* __restrict__ bias, void* __restrict__ out,
    int K, int M, int mode) {
  __shared__ __align__(16) bf16 As[128 * 32];
  __shared__ __align__(16) bf16 Bs[128 * 32];
  const int row0 = blockIdx.y * 128, col0 = blockIdx.x * 128;

  v4f acc[4][4];
  v4f z4 = {0.f, 0.f, 0.f, 0.f};
#pragma unroll
  for (int mi = 0; mi < 4; mi++)
#pragma unroll
    for (int ni = 0; ni < 4; ni++) acc[mi][ni] = z4;

  gemm_core(X, W, K, 0, K, row0, col0, As, Bs, acc);

  // epilogue: C/D layout col = lane&15, row = (lane>>4)*4 + reg
  const int lane = threadIdx.x & 63;
  const int w = threadIdx.x >> 6, wm = w >> 1, wn = w & 1;
  const int lr = lane & 15, lq = lane >> 4;
#pragma unroll
  for (int ni = 0; ni < 4; ni++) {
    int col = col0 + wn * 64 + ni * 16 + lr;
    float bv = bias[col];
#pragma unroll
    for (int mi = 0; mi < 4; mi++) {
#pragma unroll
      for (int i = 0; i < 4; i++) {
        int row = row0 + wm * 64 + mi * 16 + lq * 4 + i;
        float v = acc[mi][ni][i] + bv;
        if (mode == MODE_GELU) {
          v = 0.5f * v * (1.f + erff(v * 0.70710678118654752f));
          ((bf16*)out)[(size_t)row * M + col] = (bf16)v;
        } else {
          ((float*)out)[(size_t)row * M + col] = v;
        }
      }
    }
  }
}

// ---------------------------------------------------------------------------
// Split-K=2 MFMA GEMM for the under-filled 768-col GEMMs (Wo, W2).
// Grid (M/128, N/128, 2): z-slice sums k in [z*K/2, (z+1)*K/2) into its own
// partial buffer (bias folded into slice 0). Downstream ln_fused adds the
// two partials during its residual pass — no atomics, no ordering needed.
// ---------------------------------------------------------------------------
__global__ __launch_bounds__(256) void gemm_splitk(
    const bf16* __restrict__ X, const bf16* __restrict__ W,
    const float* __restrict__ bias,
    float* __restrict__ out0, float* __restrict__ out1, int K, int M) {
  __shared__ __align__(16) bf16 As[128 * 32];
  __shared__ __align__(16) bf16 Bs[128 * 32];
  const int row0 = blockIdx.y * 128, col0 = blockIdx.x * 128;
  const int z = blockIdx.z;
  const int kh = K >> 1;
  float* outp = z ? out1 : out0;

  v4f acc[4][4];
  v4f z4 = {0.f, 0.f, 0.f, 0.f};
#pragma unroll
  for (int mi = 0; mi < 4; mi++)
#pragma unroll
    for (int ni = 0; ni < 4; ni++) acc[mi][ni] = z4;

  gemm_core(X, W, K, z * kh, z * kh + kh, row0, col0, As, Bs, acc);

  const int lane = threadIdx.x & 63;
  const int w = threadIdx.x >> 6, wm = w >> 1, wn = w & 1;
  const int lr = lane & 15, lq = lane >> 4;
#pragma unroll
  for (int ni = 0; ni < 4; ni++) {
    int col = col0 + wn * 64 + ni * 16 + lr;
    float bv = z ? 0.f : bias[col];
#pragma unroll
    for (int mi = 0; mi < 4; mi++) {
#pragma unroll
      for (int i = 0; i < 4; i++) {
        int row = row0 + wm * 64 + mi * 16 + lq * 4 + i;
        outp[(size_t)row * M + col] = acc[mi][ni][i] + bv;
      }
    }
  }
}

// ---------------------------------------------------------------------------
// Fused QKV MFMA GEMM with head-major scatter epilogue.
// Grid (18, 32): blockIdx.x/6 selects q/k/v, %6 is the 128-col tile.
// q is scaled by 0.125/32 = 1/256 after bias.
// ---------------------------------------------------------------------------
__global__ __launch_bounds__(256) void qkv_mfma(
    const bf16* __restrict__ Xb,
    const bf16* __restrict__ Wqb, const bf16* __restrict__ Wkb,
    const bf16* __restrict__ Wvb,
    const float* __restrict__ bq, const float* __restrict__ bk,
    const float* __restrict__ bv,
    float* __restrict__ qh, float* __restrict__ kh, float* __restrict__ vh) {
  __shared__ __align__(16) bf16 As[128 * 32];
  __shared__ __align__(16) bf16 Bs[128 * 32];
  const int third = blockIdx.x / 6;
  const int xt    = blockIdx.x % 6;
  const bf16*  W    = third == 0 ? Wqb : (third == 1 ? Wkb : Wvb);
  const float* bias = third == 0 ? bq  : (third == 1 ? bk  : bv);
  float*       outp = third == 0 ? qh  : (third == 1 ? kh  : vh);
  const float scale = third == 0 ? (0.125f / 32.f) : 1.f;
  const int row0 = blockIdx.y * 128, col0 = xt * 128;

  v4f acc[4][4];
  v4f z4 = {0.f, 0.f, 0.f, 0.f};
#pragma unroll
  for (int mi = 0; mi < 4; mi++)
#pragma unroll
    for (int ni = 0; ni < 4; ni++) acc[mi][ni] = z4;

  gemm_core(Xb, W, D_, 0, D_, row0, col0, As, Bs, acc);

  const int lane = threadIdx.x & 63;
  const int w = threadIdx.x >> 6, wm = w >> 1, wn = w & 1;
  const int lr = lane & 15, lq = lane >> 4;
#pragma unroll
  for (int ni = 0; ni < 4; ni++) {
    int col = col0 + wn * 64 + ni * 16 + lr;
    float bvv = bias[col];
    int h = col >> 6, hd = col & 63;
#pragma unroll
    for (int mi = 0; mi < 4; mi++) {
#pragma unroll
      for (int i = 0; i < 4; i++) {
        int row = row0 + wm * 64 + mi * 16 + lq * 4 + i; // token = t*B + bb
        int t = row >> 2, bb = row & 3;
        float v = (acc[mi][ni][i] + bvv) * scale;
        outp[(((size_t)(bb * H_ + h)) * T_ + t) * HD_ + hd] = v;
      }
    }
  }
}

// ---------------------------------------------------------------------------
// Flash attention (fp32 compute), ctx written as bf16 (feeds Wo MFMA GEMM).
// Fused in:
//  - gate: per-row mask scale ga*(gb*grep_a[h]-1)+2 computed inline from q
//    (each block owns exactly the 64 q-rows its msc values come from)
//  - bias pass-through: the positional_bias tile read here is streamed to
//    bias_out (second kernel output) with nontemporal stores (read-once).
// Bias loads are nontemporal too: 192 MB single-touch stream must not evict
// the K/V working set (512 KB/head, reused by 16 row-blocks) from L2.
// ---------------------------------------------------------------------------
__global__ __launch_bounds__(256) void flash_attn(
    const float* __restrict__ Q, const float* __restrict__ Kh,
    const float* __restrict__ Vh, const float* __restrict__ bias,
    const float* __restrict__ grep_w, const float* __restrict__ grep_b,
    const float* __restrict__ grep_a,
    bf16* __restrict__ ctx, float* __restrict__ bias_out) {
  __shared__ float Qs[64][68];
  __shared__ float Ks[64][68];
  __shared__ float Vs[64][68];
  int n  = blockIdx.y;
  int rb = blockIdx.x * 64;
  int tid = threadIdx.x;
  int r = tid >> 3;   // 0..31
  int c = tid & 7;    // 0..7
  int b = n / H_, h = n % H_;
  const float* Qp = Q  + (size_t)n * T_ * HD_;
  const float* Kp = Kh + (size_t)n * T_ * HD_;
  const float* Vp = Vh + (size_t)n * T_ * HD_;

  {
    int qr = tid >> 2, qs = (tid & 3) * 16;
    const float4* src = (const float4*)(Qp + (size_t)(rb + qr) * HD_ + qs);
    float4* dst = (float4*)&Qs[qr][qs];
    dst[0] = src[0]; dst[1] = src[1]; dst[2] = src[2]; dst[3] = src[3];
  }

  // ---- inline gate: ms = ga*(gb*grep_a[h]-1)+2, q_full = q*256 ----------
  float ms0, ms1;
  {
    const float* q0 = Qp + (size_t)(rb + r) * HD_ + c * 8;
    const float* q1 = Qp + (size_t)(rb + r + 32) * HD_ + c * 8;
    float4 qa0 = *(const float4*)q0, qa1 = *(const float4*)(q0 + 4);
    float4 qb0 = *(const float4*)q1, qb1 = *(const float4*)(q1 + 4);
    float qv0[8] = {qa0.x, qa0.y, qa0.z, qa0.w, qa1.x, qa1.y, qa1.z, qa1.w};
    float qv1[8] = {qb0.x, qb0.y, qb0.z, qb0.w, qb1.x, qb1.y, qb1.z, qb1.w};
    float z0[8], z1[8];
#pragma unroll
    for (int o = 0; o < 8; o++) {
      const float* gw = grep_w + o * 64 + c * 8;
      float a0 = 0.f, a1 = 0.f;
#pragma unroll
      for (int j = 0; j < 8; j++) {
        float wv = gw[j];
        a0 += qv0[j] * wv;
        a1 += qv1[j] * wv;
      }
      z0[o] = a0; z1[o] = a1;
    }
#pragma unroll
    for (int off = 1; off < 8; off <<= 1)
#pragma unroll
      for (int o = 0; o < 8; o++) {
        z0[o] += __shfl_xor(z0[o], off);
        z1[o] += __shfl_xor(z1[o], off);
      }
    float gb03 = grep_b[0] + grep_b[1] + grep_b[2] + grep_b[3];
    float gb47 = grep_b[4] + grep_b[5] + grep_b[6] + grep_b[7];
    float ga_h = grep_a[h];
    float s0a = (z0[0] + z0[1] + z0[2] + z0[3]) * 256.f + gb03;
    float s1a = (z0[4] + z0[5] + z0[6] + z0[7]) * 256.f + gb47;
    float s0b = (z1[0] + z1[1] + z1[2] + z1[3]) * 256.f + gb03;
    float s1b = (z1[4] + z1[5] + z1[6] + z1[7]) * 256.f + gb47;
    float gaa = 1.f / (1.f + __expf(-s0a));
    float gba = 1.f / (1.f + __expf(-s1a));
    float gab = 1.f / (1.f + __expf(-s0b));
    float gbb = 1.f / (1.f + __expf(-s1b));
    ms0 = gaa * (gba * ga_h - 1.f) + 2.f;
    ms1 = gab * (gbb * ga_h - 1.f) + 2.f;
  }

  float m0 = -1e30f, m1 = -1e30f, l0 = 0.f, l1 = 0.f;
  float O0[8], O1[8];
#pragma unroll
  for (int d = 0; d < 8; d++) { O0[d] = 0.f; O1[d] = 0.f; }
  const float* br0 = bias + ((size_t)n * T_ + rb + r) * T_;
  const float* br1 = bias + ((size_t)n * T_ + rb + r + 32) * T_;
  float* bo0 = bias_out + ((size_t)n * T_ + rb + r) * T_;
  float* bo1 = bias_out + ((size_t)n * T_ + rb + r + 32) * T_;

  for (int cb = 0; cb < T_; cb += 64) {
    __syncthreads();
    {
      int kr = tid >> 2, ks = (tid & 3) * 16;
      const float4* sk = (const float4*)(Kp + (size_t)(cb + kr) * HD_ + ks);
      const float4* sv = (const float4*)(Vp + (size_t)(cb + kr) * HD_ + ks);
      float4* dk = (float4*)&Ks[kr][ks];
      float4* dv = (float4*)&Vs[kr][ks];
      dk[0] = sk[0]; dk[1] = sk[1]; dk[2] = sk[2]; dk[3] = sk[3];
      dv[0] = sv[0]; dv[1] = sv[1]; dv[2] = sv[2]; dv[3] = sv[3];
    }
    __syncthreads();

    float p0[8], p1[8];
#pragma unroll
    for (int sj = 0; sj < 8; sj++) { p0[sj] = 0.f; p1[sj] = 0.f; }
    for (int k4 = 0; k4 < 64; k4 += 4) {
      float4 qa = *(const float4*)&Qs[r][k4];
      float4 qb = *(const float4*)&Qs[r + 32][k4];
#pragma unroll
      for (int sj = 0; sj < 8; sj++) {
        int s = sj * 8 + c;
        float4 kv = *(const float4*)&Ks[s][k4];
        p0[sj] += qa.x * kv.x + qa.y * kv.y + qa.z * kv.z + qa.w * kv.w;
        p1[sj] += qb.x * kv.x + qb.y * kv.y + qb.z * kv.z + qb.w * kv.w;
      }
    }
    float tmax0 = -1e30f, tmax1 = -1e30f;
#pragma unroll
    for (int sj = 0; sj < 8; sj++) {
      int s = sj * 8 + c;
      float bv0 = __builtin_nontemporal_load(&br0[cb + s]);
      float bv1 = __builtin_nontemporal_load(&br1[cb + s]);
      __builtin_nontemporal_store(bv0, &bo0[cb + s]);
      __builtin_nontemporal_store(bv1, &bo1[cb + s]);
      p0[sj] = p0[sj] * 32.f + ms0 * bv0;
      p1[sj] = p1[sj] * 32.f + ms1 * bv1;
      tmax0 = fmaxf(tmax0, p0[sj]);
      tmax1 = fmaxf(tmax1, p1[sj]);
    }
#pragma unroll
    for (int off = 1; off < 8; off <<= 1) {
      tmax0 = fmaxf(tmax0, __shfl_xor(tmax0, off));
      tmax1 = fmaxf(tmax1, __shfl_xor(tmax1, off));
    }
    float mn0 = fmaxf(m0, tmax0), mn1 = fmaxf(m1, tmax1);
    float al0 = __expf(m0 - mn0), al1 = __expf(m1 - mn1);
    float ls0 = 0.f, ls1 = 0.f;
#pragma unroll
    for (int sj = 0; sj < 8; sj++) {
      p0[sj] = __expf(p0[sj] - mn0); ls0 += p0[sj];
      p1[sj] = __expf(p1[sj] - mn1); ls1 += p1[sj];
    }
#pragma unroll
    for (int off = 1; off < 8; off <<= 1) {
      ls0 += __shfl_xor(ls0, off);
      ls1 += __shfl_xor(ls1, off);
    }
    l0 = l0 * al0 + ls0;
    l1 = l1 * al1 + ls1;
    m0 = mn0; m1 = mn1;
#pragma unroll
    for (int d = 0; d < 8; d++) { O0[d] *= al0; O1[d] *= al1; }

#pragma unroll
    for (int sj = 0; sj < 8; sj++) {
#pragma unroll
      for (int cc = 0; cc < 8; cc++) {
        int src = (tid & 56) | cc;
        float pa = __shfl(p0[sj], src);
        float pb = __shfl(p1[sj], src);
        int s2 = sj * 8 + cc;
        const float4* vv = (const float4*)&Vs[s2][c * 8];
        float4 va = vv[0], vb = vv[1];
        O0[0] += pa * va.x; O0[1] += pa * va.y; O0[2] += pa * va.z; O0[3] += pa * va.w;
        O0[4] += pa * vb.x; O0[5] += pa * vb.y; O0[6] += pa * vb.z; O0[7] += pa * vb.w;
        O1[0] += pb * va.x; O1[1] += pb * va.y; O1[2] += pb * va.z; O1[3] += pb * va.w;
        O1[4] += pb * vb.x; O1[5] += pb * vb.y; O1[6] += pb * vb.z; O1[7] += pb * vb.w;
      }
    }
  }

  float inv0 = 1.f / l0, inv1 = 1.f / l1;
  int t0 = rb + r, t1 = rb + r + 32;
  bf16* o0 = ctx + ((size_t)(t0 * B_ + b)) * D_ + h * HD_ + c * 8;
  bf16* o1 = ctx + ((size_t)(t1 * B_ + b)) * D_ + h * HD_ + c * 8;
#pragma unroll
  for (int d = 0; d < 8; d++) {
    o0[d] = (bf16)(O0[d] * inv0);
    o1[d] = (bf16)(O1[d] * inv1);
  }
}

// ---------------------------------------------------------------------------
// Fused residual + LayerNorm with split-K partial merge:
//   out = LN(A*alpha + R1 + R2)*g + b, optional bf16 copy.
// ---------------------------------------------------------------------------
__global__ __launch_bounds__(256) void ln_fused(
    const float* __restrict__ A, const float* __restrict__ R1,
    const float* __restrict__ R2,
    const float* __restrict__ g, const float* __restrict__ be,
    float* __restrict__ out, bf16* __restrict__ outb, float alpha) {
  int row = blockIdx.x, tid = threadIdx.x;
  const float* a  = A  + (size_t)row * D_;
  const float* r1 = R1 + (size_t)row * D_;
  const float* r2 = R2 + (size_t)row * D_;
  float v[3];
  float s = 0.f, s2 = 0.f;
#pragma unroll
  for (int j = 0; j < 3; j++) {
    int col = tid + j * 256;
    float x = a[col] * alpha + r1[col] + r2[col];
    v[j] = x; s += x; s2 += x * x;
  }
  __shared__ float red[8];
#pragma unroll
  for (int off = 32; off >= 1; off >>= 1) {
    s  += __shfl_down(s, off);
    s2 += __shfl_down(s2, off);
  }
  int wv = tid >> 6;
  if ((tid & 63) == 0) { red[wv] = s; red[4 + wv] = s2; }
  __syncthreads();
  s  = red[0] + red[1] + red[2] + red[3];
  s2 = red[4] + red[5] + red[6] + red[7];
  float mu  = s * (1.f / 768.f);
  float var = s2 * (1.f / 768.f) - mu * mu;
  float inv = rsqrtf(var + 1e-5f);
#pragma unroll
  for (int j = 0; j < 3; j++) {
    int col = tid + j * 256;
    float y = (v[j] - mu) * inv * g[col] + be[col];
    out[(size_t)row * D_ + col] = y;
    if (outb) outb[(size_t)row * D_ + col] = (bf16)y;
  }
}

// ---------------------------------------------------------------------------
extern "C" void kernel_launch(void* const* d_in, const int* in_sizes, int n_in,
                              void* d_out, int out_size, void* d_ws, size_t ws_size,
                              hipStream_t stream) {
  const float* states = (const float*)d_in[0];
  const float* pbias  = (const float*)d_in[1];
  const float* Wq = (const float*)d_in[2];
  const float* bq = (const float*)d_in[3];
  const float* Wk = (const float*)d_in[4];
  const float* bk = (const float*)d_in[5];
  const float* Wv = (const float*)d_in[6];
  const float* bv = (const float*)d_in[7];
  const float* Wo = (const float*)d_in[8];
  const float* bo = (const float*)d_in[9];
  const float* grep_w = (const float*)d_in[10];
  const float* grep_b = (const float*)d_in[11];
  const float* grep_a = (const float*)d_in[12];
  const float* ln1_g = (const float*)d_in[13];
  const float* ln1_b = (const float*)d_in[14];
  const float* W1 = (const float*)d_in[15];
  const float* b1 = (const float*)d_in[16];
  const float* W2 = (const float*)d_in[17];
  const float* b2 = (const float*)d_in[18];
  const float* ln2_g = (const float*)d_in[19];
  const float* ln2_b = (const float*)d_in[20];

  float* ws = (float*)d_ws;
  float* qh   = ws;                  // 3,145,728 f32
  float* kh   = ws + 3145728;        // 3,145,728
  float* vh   = ws + 6291456;        // 3,145,728
  bf16* states_bf = (bf16*)(ws + 9486336);   // 3,145,728 bf16
  bf16* ctx_bf    = (bf16*)(ws + 11059200);  // 3,145,728 bf16
  bf16* x_bf      = (bf16*)(ws + 12632064);  // 3,145,728 bf16
  bf16* h1_bf     = (bf16*)(ws + 14204928);  // 12,582,912 bf16
  bf16* wq_bf     = (bf16*)(ws + 20496384);  // 589,824 bf16
  bf16* wk_bf     = (bf16*)(ws + 20791296);
  bf16* wv_bf     = (bf16*)(ws + 21086208);
  bf16* wo_bf     = (bf16*)(ws + 21381120);
  bf16* w1_bf     = (bf16*)(ws + 21676032);  // 2,359,296 bf16
  bf16* w2_bf     = (bf16*)(ws + 22855680);  // ends at 24,035,328 f32 (~96 MB)
  // buffer reuse timeline (no new workspace):
  //   after flash: qh,kh,vh all dead
  //   Wo partials  -> qh (z=0), kh (z=1)
  //   x (ln1 out)  -> vh ; x_bf for FFN
  //   after ln1: qh,kh dead again
  //   W2 partials  -> qh (z=0), kh (z=1)
  //   ln2 reads vh,qh,kh -> d_out
  float* attn_a = qh;
  float* attn_b = kh;
  float* x      = vh;
  float* h2_a   = qh;
  float* h2_b   = kh;
  float* outp = (float*)d_out;

  dim3 blk(256);
  // all fp32 -> bf16 casts in ONE launch
  cast_all<<<9984, blk, 0, stream>>>(
      (const float4*)states, (const float4*)Wq, (const float4*)Wk,
      (const float4*)Wv, (const float4*)Wo, (const float4*)W1,
      (const float4*)W2,
      (v4bf*)states_bf, (v4bf*)wq_bf, (v4bf*)wk_bf, (v4bf*)wv_bf,
      (v4bf*)wo_bf, (v4bf*)w1_bf, (v4bf*)w2_bf);

  // fused QKV (MFMA), head-major outputs, q scaled by 1/256
  qkv_mfma<<<dim3(18, 32), blk, 0, stream>>>(states_bf, wq_bf, wk_bf, wv_bf,
                                             bq, bk, bv, qh, kh, vh);
  // fused attention (gate inline) -> ctx (bf16, token-major (T,B,D));
  // also streams positional_bias through to the second output
  flash_attn<<<dim3(16, 48), blk, 0, stream>>>(qh, kh, vh, pbias,
                                               grep_w, grep_b, grep_a,
                                               ctx_bf, outp + 3145728);
  // output projection (MFMA, split-K=2 -> 384 blocks)
  gemm_splitk<<<dim3(6, 32, 2), blk, 0, stream>>>(ctx_bf, wo_bf, bo,
                                                  attn_a, attn_b, 768, 768);
  // x = LN(states*ALPHA + attn_a + attn_b), also emit bf16 copy for FFN
  ln_fused<<<4096, blk, 0, stream>>>(states, attn_a, attn_b, ln1_g, ln1_b,
                                     x, x_bf, ALPHA_);
  // FFN (MFMA): GELU epilogue writes bf16 h1 directly (768 blocks, no split)
  gemm_mfma<<<dim3(24, 32), blk, 0, stream>>>(x_bf, w1_bf, b1, h1_bf, 768, 3072, MODE_GELU);
  // second FFN GEMM (MFMA, split-K=2 -> 384 blocks)
  gemm_splitk<<<dim3(6, 32, 2), blk, 0, stream>>>(h1_bf, w2_bf, b2,
                                                  h2_a, h2_b, 3072, 768);
  // out = LN(h2_a + h2_b + x*ALPHA)
  ln_fused<<<4096, blk, 0, stream>>>(x, h2_a, h2_b, ln2_g, ln2_b,
                                     outp, (bf16*)nullptr, ALPHA_);
}

// Round 7
// 886.916 us; speedup vs baseline: 1.0726x; 1.0726x over previous
//
#include <hip/hip_runtime.h>
#include <hip/hip_bf16.h>

// Problem constants
#define T_    1024
#define B_    4
#define D_    768
#define H_    12
#define HD_   64
#define FF_   3072

typedef __bf16 bf16;
typedef __bf16 v8bf __attribute__((ext_vector_type(8)));
typedef __bf16 v4bf __attribute__((ext_vector_type(4)));
typedef float  v4f  __attribute__((ext_vector_type(4)));

#define AS1 __attribute__((address_space(1)))
#define AS3 __attribute__((address_space(3)))
// async global->LDS, 16B per lane, deposit = wave-uniform base + lane*16
#define GLOAD_LDS(g, l) __builtin_amdgcn_global_load_lds((AS1 void*)(g), (AS3 void*)(l), 16, 0, 0)

static const float ALPHA_ = 2.2133638394006434f; // 24^0.25

#define MODE_PLAIN 0
#define MODE_GELU  1

// ---------------------------------------------------------------------------
// Fused fp32 -> bf16 cast for ALL tensors in one launch.
// ---------------------------------------------------------------------------
#define SEG0 786432            // states end
#define SEG1 (SEG0 + 147456)   // Wq end
#define SEG2 (SEG1 + 147456)   // Wk end
#define SEG3 (SEG2 + 147456)   // Wv end
#define SEG4 (SEG3 + 147456)   // Wo end
#define SEG5 (SEG4 + 589824)   // W1 end
#define SEG6 (SEG5 + 589824)   // W2 end (= 2555904)

__global__ __launch_bounds__(256) void cast_all(
    const float4* __restrict__ states, const float4* __restrict__ wq,
    const float4* __restrict__ wk, const float4* __restrict__ wv,
    const float4* __restrict__ wo, const float4* __restrict__ w1,
    const float4* __restrict__ w2,
    v4bf* __restrict__ o_states, v4bf* __restrict__ o_wq,
    v4bf* __restrict__ o_wk, v4bf* __restrict__ o_wv,
    v4bf* __restrict__ o_wo, v4bf* __restrict__ o_w1,
    v4bf* __restrict__ o_w2) {
  int i = blockIdx.x * 256 + threadIdx.x;
  const float4* src; v4bf* dst; int off;
  if      (i < SEG0) { src = states; dst = o_states; off = 0;    }
  else if (i < SEG1) { src = wq;     dst = o_wq;     off = SEG0; }
  else if (i < SEG2) { src = wk;     dst = o_wk;     off = SEG1; }
  else if (i < SEG3) { src = wv;     dst = o_wv;     off = SEG2; }
  else if (i < SEG4) { src = wo;     dst = o_wo;     off = SEG3; }
  else if (i < SEG5) { src = w1;     dst = o_w1;     off = SEG4; }
  else               { src = w2;     dst = o_w2;     off = SEG5; }
  float4 v = src[i - off];
  v4bf o;
  o[0] = (bf16)v.x; o[1] = (bf16)v.y; o[2] = (bf16)v.z; o[3] = (bf16)v.w;
  dst[i - off] = o;
}

// ---------------------------------------------------------------------------
// MFMA GEMM core (verified): Out(128x128) = X(NxK) @ W(MxK)^T over [kBeg,kEnd).
// ---------------------------------------------------------------------------
__device__ __forceinline__ void gemm_core(
    const bf16* __restrict__ X, const bf16* __restrict__ W, int K,
    int kBeg, int kEnd,
    int row0, int col0, bf16* As, bf16* Bs, v4f (&acc)[4][4]) {
  const int tid  = threadIdx.x;
  const int lane = tid & 63;
  const int w    = tid >> 6;        // wave 0..3
  const int wm   = w >> 1, wn = w & 1;
  const int lr   = lane & 15;       // row within 16-row group
  const int lq   = lane >> 4;       // k-quad 0..3 (8 bf16 = 16B each)

  const bf16* xg0 = X + (size_t)(row0 + 16 * w       + lr) * K + lq * 8;
  const bf16* xg1 = X + (size_t)(row0 + 16 * (w + 4) + lr) * K + lq * 8;
  const bf16* wg0 = W + (size_t)(col0 + 16 * w       + lr) * K + lq * 8;
  const bf16* wg1 = W + (size_t)(col0 + 16 * (w + 4) + lr) * K + lq * 8;
  char* AsB = (char*)As;
  char* BsB = (char*)Bs;

  for (int k0 = kBeg; k0 < kEnd; k0 += 32) {
    __syncthreads();
    GLOAD_LDS(xg0 + k0, AsB + w * 1024);
    GLOAD_LDS(xg1 + k0, AsB + (w + 4) * 1024);
    GLOAD_LDS(wg0 + k0, BsB + w * 1024);
    GLOAD_LDS(wg1 + k0, BsB + (w + 4) * 1024);
    __syncthreads();

    v8bf af[4], bw[4];
#pragma unroll
    for (int mi = 0; mi < 4; mi++)
      af[mi] = *(const v8bf*)(AsB + (wm * 4 + mi) * 1024 + lane * 16);
#pragma unroll
    for (int ni = 0; ni < 4; ni++)
      bw[ni] = *(const v8bf*)(BsB + (wn * 4 + ni) * 1024 + lane * 16);
#pragma unroll
    for (int mi = 0; mi < 4; mi++)
#pragma unroll
      for (int ni = 0; ni < 4; ni++)
        acc[mi][ni] = __builtin_amdgcn_mfma_f32_16x16x32_bf16(
            af[mi], bw[ni], acc[mi][ni], 0, 0, 0);
  }
}

// ---------------------------------------------------------------------------
// Generic MFMA GEMM: out = X @ W^T + bias, PLAIN(f32) or GELU(bf16) epilogue.
// ---------------------------------------------------------------------------
__global__ __launch_bounds__(256) void gemm_mfma(
    const bf16* __restrict__ X, const bf16* __restrict__ W,
    const float* __restrict__ bias, void* __restrict__ out,
    int K, int M, int mode) {
  __shared__ __align__(16) bf16 As[128 * 32];
  __shared__ __align__(16) bf16 Bs[128 * 32];
  const int row0 = blockIdx.y * 128, col0 = blockIdx.x * 128;

  v4f acc[4][4];
  v4f z4 = {0.f, 0.f, 0.f, 0.f};
#pragma unroll
  for (int mi = 0; mi < 4; mi++)
#pragma unroll
    for (int ni = 0; ni < 4; ni++) acc[mi][ni] = z4;

  gemm_core(X, W, K, 0, K, row0, col0, As, Bs, acc);

  const int lane = threadIdx.x & 63;
  const int w = threadIdx.x >> 6, wm = w >> 1, wn = w & 1;
  const int lr = lane & 15, lq = lane >> 4;
#pragma unroll
  for (int ni = 0; ni < 4; ni++) {
    int col = col0 + wn * 64 + ni * 16 + lr;
    float bv = bias[col];
#pragma unroll
    for (int mi = 0; mi < 4; mi++) {
#pragma unroll
      for (int i = 0; i < 4; i++) {
        int row = row0 + wm * 64 + mi * 16 + lq * 4 + i;
        float v = acc[mi][ni][i] + bv;
        if (mode == MODE_GELU) {
          v = 0.5f * v * (1.f + erff(v * 0.70710678118654752f));
          ((bf16*)out)[(size_t)row * M + col] = (bf16)v;
        } else {
          ((float*)out)[(size_t)row * M + col] = v;
        }
      }
    }
  }
}

// ---------------------------------------------------------------------------
// Split-K=2 MFMA GEMM for the under-filled 768-col GEMMs (Wo, W2).
// ---------------------------------------------------------------------------
__global__ __launch_bounds__(256) void gemm_splitk(
    const bf16* __restrict__ X, const bf16* __restrict__ W,
    const float* __restrict__ bias,
    float* __restrict__ out0, float* __restrict__ out1, int K, int M) {
  __shared__ __align__(16) bf16 As[128 * 32];
  __shared__ __align__(16) bf16 Bs[128 * 32];
  const int row0 = blockIdx.y * 128, col0 = blockIdx.x * 128;
  const int z = blockIdx.z;
  const int kh = K >> 1;
  float* outp = z ? out1 : out0;

  v4f acc[4][4];
  v4f z4 = {0.f, 0.f, 0.f, 0.f};
#pragma unroll
  for (int mi = 0; mi < 4; mi++)
#pragma unroll
    for (int ni = 0; ni < 4; ni++) acc[mi][ni] = z4;

  gemm_core(X, W, K, z * kh, z * kh + kh, row0, col0, As, Bs, acc);

  const int lane = threadIdx.x & 63;
  const int w = threadIdx.x >> 6, wm = w >> 1, wn = w & 1;
  const int lr = lane & 15, lq = lane >> 4;
#pragma unroll
  for (int ni = 0; ni < 4; ni++) {
    int col = col0 + wn * 64 + ni * 16 + lr;
    float bv = z ? 0.f : bias[col];
#pragma unroll
    for (int mi = 0; mi < 4; mi++) {
#pragma unroll
      for (int i = 0; i < 4; i++) {
        int row = row0 + wm * 64 + mi * 16 + lq * 4 + i;
        outp[(size_t)row * M + col] = acc[mi][ni][i] + bv;
      }
    }
  }
}

// ---------------------------------------------------------------------------
// Fused QKV MFMA GEMM.  q: writes qh fp32 (for gate) AND q_bf (fragment-tiled
// bf16).  k/v: write ONLY fragment-tiled bf16 (k_bf / v_bf) for MFMA flash.
// Tiled layouts (per head n):
//   q/k:  block = ((n*64 + (t>>4))*2 + (hd>>5)); within-block lane
//         l = (t&15) | (((hd>>3)&3)<<4), j = hd&7  -> A/B fragment order.
//   v^T:  block = ((n*32 + (t>>5))*4 + (hd>>4)); lane
//         l = (hd&15) | (((t>>3)&3)<<4), j = t&7   -> B fragment of V^T.
// ---------------------------------------------------------------------------
__global__ __launch_bounds__(256) void qkv_mfma(
    const bf16* __restrict__ Xb,
    const bf16* __restrict__ Wqb, const bf16* __restrict__ Wkb,
    const bf16* __restrict__ Wvb,
    const float* __restrict__ bq, const float* __restrict__ bk,
    const float* __restrict__ bv,
    float* __restrict__ qh, bf16* __restrict__ qbf,
    bf16* __restrict__ kbf, bf16* __restrict__ vbf) {
  __shared__ __align__(16) bf16 As[128 * 32];
  __shared__ __align__(16) bf16 Bs[128 * 32];
  const int third = blockIdx.x / 6;
  const int xt    = blockIdx.x % 6;
  const bf16*  W    = third == 0 ? Wqb : (third == 1 ? Wkb : Wvb);
  const float* bias = third == 0 ? bq  : (third == 1 ? bk  : bv);
  const int row0 = blockIdx.y * 128, col0 = xt * 128;

  v4f acc[4][4];
  v4f z4 = {0.f, 0.f, 0.f, 0.f};
#pragma unroll
  for (int mi = 0; mi < 4; mi++)
#pragma unroll
    for (int ni = 0; ni < 4; ni++) acc[mi][ni] = z4;

  gemm_core(Xb, W, D_, 0, D_, row0, col0, As, Bs, acc);

  const int lane = threadIdx.x & 63;
  const int w = threadIdx.x >> 6, wm = w >> 1, wn = w & 1;
  const int lr = lane & 15, lq = lane >> 4;
#pragma unroll
  for (int ni = 0; ni < 4; ni++) {
    int col = col0 + wn * 64 + ni * 16 + lr;
    float bvv = bias[col];
    int h = col >> 6, hd = col & 63;
#pragma unroll
    for (int mi = 0; mi < 4; mi++) {
#pragma unroll
      for (int i = 0; i < 4; i++) {
        int row = row0 + wm * 64 + mi * 16 + lq * 4 + i; // token = t*B + bb
        int t = row >> 2, bb = row & 3;
        int n2 = bb * H_ + h;
        float v = acc[mi][ni][i] + bvv;
        if (third == 0) {
          v *= (0.125f / 32.f);
          qh[(((size_t)n2) * T_ + t) * HD_ + hd] = v;
          size_t idx = (((size_t)n2 * 64 + (t >> 4)) * 2 + (hd >> 5)) * 512
                     + (((t & 15) | (((hd >> 3) & 3) << 4)) << 3) + (hd & 7);
          qbf[idx] = (bf16)v;
        } else if (third == 1) {
          size_t idx = (((size_t)n2 * 64 + (t >> 4)) * 2 + (hd >> 5)) * 512
                     + (((t & 15) | (((hd >> 3) & 3) << 4)) << 3) + (hd & 7);
          kbf[idx] = (bf16)v;
        } else {
          size_t idx = (((size_t)n2 * 32 + (t >> 5)) * 4 + (hd >> 4)) * 512
                     + (((hd & 15) | (((t >> 3) & 3) << 4)) << 3) + (t & 7);
          vbf[idx] = (bf16)v;
        }
      }
    }
  }
}

// ---------------------------------------------------------------------------
// MFMA flash attention.  Per block: head n, 64 q-rows; 4 waves x 16 rows.
// Fragments load directly from tiled global buffers (no K/V LDS).
// LDS: bias tile [64][68] f32 (coalesced staging + pass-through to bias_out)
//      + per-wave 2KB P buffer (C-layout -> A-fragment reorder).
// Gate fused (from qh fp32).  Softmax in MFMA C-layout:
//   col s = 16*ct + (lane&15), row r = 16*w + (lane>>4)*4 + i.
// ---------------------------------------------------------------------------
__global__ __launch_bounds__(256) void flash_attn(
    const float* __restrict__ Q, const bf16* __restrict__ Qt,
    const bf16* __restrict__ Kt, const bf16* __restrict__ Vt,
    const float* __restrict__ bias,
    const float* __restrict__ grep_w, const float* __restrict__ grep_b,
    const float* __restrict__ grep_a,
    bf16* __restrict__ ctx, float* __restrict__ bias_out) {
  __shared__ float Bls[64][68];
  __shared__ __align__(16) bf16 Pbuf[4][1024];
  const int n  = blockIdx.y;
  const int R0 = blockIdx.x * 64;
  const int tid = threadIdx.x;
  const int l  = tid & 63, w = tid >> 6;
  const int lo = l & 15, hi = l >> 4;
  const int b = n / H_, h = n % H_;

  // ---- gate for this wave's 16 rows (row = R0+16w+lo, d-slice hi*16..+15)
  float ms;
  {
    const float* qrow = Q + (((size_t)n * T_ + R0 + 16 * w + lo)) * HD_ + hi * 16;
    float4 qa = *(const float4*)qrow;
    float4 qb2 = *(const float4*)(qrow + 4);
    float4 qc = *(const float4*)(qrow + 8);
    float4 qd = *(const float4*)(qrow + 12);
    float qv[16] = {qa.x, qa.y, qa.z, qa.w, qb2.x, qb2.y, qb2.z, qb2.w,
                    qc.x, qc.y, qc.z, qc.w, qd.x, qd.y, qd.z, qd.w};
    float z[8];
#pragma unroll
    for (int o = 0; o < 8; o++) {
      const float* gw = grep_w + o * 64 + hi * 16;
      float a = 0.f;
#pragma unroll
      for (int j = 0; j < 16; j++) a += qv[j] * gw[j];
      z[o] = a;
    }
#pragma unroll
    for (int o = 0; o < 8; o++) {
      z[o] += __shfl_xor(z[o], 16);
      z[o] += __shfl_xor(z[o], 32);
    }
    float gb03 = grep_b[0] + grep_b[1] + grep_b[2] + grep_b[3];
    float gb47 = grep_b[4] + grep_b[5] + grep_b[6] + grep_b[7];
    float s0 = (z[0] + z[1] + z[2] + z[3]) * 256.f + gb03;
    float s1 = (z[4] + z[5] + z[6] + z[7]) * 256.f + gb47;
    float ga = 1.f / (1.f + __expf(-s0));
    float gbv = 1.f / (1.f + __expf(-s1));
    ms = ga * (gbv * grep_a[h] - 1.f) + 2.f;
  }
  // redistribute: reg-row i needs ms of row hi*4+i (held at lane hi*4+i)
  float ms_row[4];
#pragma unroll
  for (int i = 0; i < 4; i++) ms_row[i] = __shfl(ms, hi * 4 + i);

  // ---- Q fragments (persistent): lane l -> Q[16w + (l&15)][32q + (l>>4)*8+j]
  v8bf qf[2];
  {
    const bf16* qb = Qt + (((size_t)n * 64 + (R0 >> 4) + w) * 2) * 512 + (size_t)l * 8;
    qf[0] = *(const v8bf*)qb;
    qf[1] = *(const v8bf*)(qb + 512);
  }

  float m_[4], l_[4];
  v4f acc[4];
  v4f zz = {0.f, 0.f, 0.f, 0.f};
#pragma unroll
  for (int i = 0; i < 4; i++) { m_[i] = -1e30f; l_[i] = 0.f; acc[i] = zz; }

  // ---- bias staging pointers (coalesced: row tid>>2, cols (tid&3)*16..+15)
  const int brow = tid >> 2, bc = (tid & 3) * 16;
  const float* bg = bias + ((size_t)n * T_ + R0 + brow) * T_ + bc;
  float* bo = bias_out + ((size_t)n * T_ + R0 + brow) * T_ + bc;
  v4f br4[4];
#pragma unroll
  for (int k = 0; k < 4; k++) {
    br4[k] = __builtin_nontemporal_load((const v4f*)(bg + k * 4));
    __builtin_nontemporal_store(br4[k], (v4f*)(bo + k * 4));
  }

  for (int cb = 0; cb < T_; cb += 64) {
    __syncthreads();   // previous tile's Bls reads complete
#pragma unroll
    for (int k = 0; k < 4; k++)
      *(v4f*)&Bls[brow][bc + k * 4] = br4[k];
    __syncthreads();   // bias tile ready
    if (cb + 64 < T_) {
#pragma unroll
      for (int k = 0; k < 4; k++) {
        br4[k] = __builtin_nontemporal_load((const v4f*)(bg + cb + 64 + k * 4));
        __builtin_nontemporal_store(br4[k], (v4f*)(bo + cb + 64 + k * 4));
      }
    }

    // ---- QK^T: S tile 16x64 per wave (4 col-tiles x 2 d-chunks)
    v4f sc[4];
    const bf16* kb = Kt + (((size_t)n * 64 + (cb >> 4)) * 2) * 512 + (size_t)l * 8;
#pragma unroll
    for (int ct = 0; ct < 4; ct++) {
      v8bf k0 = *(const v8bf*)(kb + ct * 1024);
      v8bf k1 = *(const v8bf*)(kb + ct * 1024 + 512);
      v4f s = zz;
      s = __builtin_amdgcn_mfma_f32_16x16x32_bf16(qf[0], k0, s, 0, 0, 0);
      s = __builtin_amdgcn_mfma_f32_16x16x32_bf16(qf[1], k1, s, 0, 0, 0);
      sc[ct] = s;
    }

    // ---- softmax (C-layout), online max/sum per reg-row
    float vals[4][4];
    float tm[4] = {-1e30f, -1e30f, -1e30f, -1e30f};
#pragma unroll
    for (int ct = 0; ct < 4; ct++)
#pragma unroll
      for (int i = 0; i < 4; i++) {
        float vv = sc[ct][i] * 32.f
                 + ms_row[i] * Bls[16 * w + hi * 4 + i][ct * 16 + lo];
        vals[ct][i] = vv;
        tm[i] = fmaxf(tm[i], vv);
      }
#pragma unroll
    for (int i = 0; i < 4; i++) {
      tm[i] = fmaxf(tm[i], __shfl_xor(tm[i], 1));
      tm[i] = fmaxf(tm[i], __shfl_xor(tm[i], 2));
      tm[i] = fmaxf(tm[i], __shfl_xor(tm[i], 4));
      tm[i] = fmaxf(tm[i], __shfl_xor(tm[i], 8));
    }
    float al[4], ls[4];
#pragma unroll
    for (int i = 0; i < 4; i++) {
      float mn = fmaxf(m_[i], tm[i]);
      al[i] = __expf(m_[i] - mn);
      m_[i] = mn;
      ls[i] = 0.f;
    }
#pragma unroll
    for (int ct = 0; ct < 4; ct++)
#pragma unroll
      for (int i = 0; i < 4; i++) {
        float p = __expf(vals[ct][i] - m_[i]);
        ls[i] += p;
        int sg = ct * 16 + lo;   // local kv col 0..63
        int idx = (sg >> 5) * 512
                + (((hi * 4 + i) | (((sg >> 3) & 3) << 4)) << 3) + (sg & 7);
        Pbuf[w][idx] = (bf16)p;
      }
#pragma unroll
    for (int i = 0; i < 4; i++) {
      ls[i] += __shfl_xor(ls[i], 1);
      ls[i] += __shfl_xor(ls[i], 2);
      ls[i] += __shfl_xor(ls[i], 4);
      ls[i] += __shfl_xor(ls[i], 8);
      l_[i] = l_[i] * al[i] + ls[i];
    }
#pragma unroll
    for (int dt = 0; dt < 4; dt++)
#pragma unroll
      for (int i = 0; i < 4; i++) acc[dt][i] *= al[i];

    // ---- PV: ctx += P(16x64) @ V(64x64); B-frags from tiled V^T global.
    // Lane-indexed A-fragment read (each lane reads ITS 8 P values).
    v8bf pf0 = *(const v8bf*)&Pbuf[w][(size_t)l * 8];
    v8bf pf1 = *(const v8bf*)&Pbuf[w][512 + (size_t)l * 8];
    const bf16* vb = Vt + (((size_t)n * 32 + (cb >> 5)) * 4) * 512 + (size_t)l * 8;
#pragma unroll
    for (int dt = 0; dt < 4; dt++) {
      v8bf v0 = *(const v8bf*)(vb + dt * 512);
      v8bf v1 = *(const v8bf*)(vb + (dt + 4) * 512);
      acc[dt] = __builtin_amdgcn_mfma_f32_16x16x32_bf16(pf0, v0, acc[dt], 0, 0, 0);
      acc[dt] = __builtin_amdgcn_mfma_f32_16x16x32_bf16(pf1, v1, acc[dt], 0, 0, 0);
    }
  }

  float inv[4];
#pragma unroll
  for (int i = 0; i < 4; i++) inv[i] = 1.f / l_[i];
#pragma unroll
  for (int dt = 0; dt < 4; dt++)
#pragma unroll
    for (int i = 0; i < 4; i++) {
      int t0 = R0 + 16 * w + hi * 4 + i;
      ctx[((size_t)(t0 * B_ + b)) * D_ + h * HD_ + dt * 16 + lo] =
          (bf16)(acc[dt][i] * inv[i]);
    }
}

// ---------------------------------------------------------------------------
// Fused residual + LayerNorm with split-K partial merge.
// ---------------------------------------------------------------------------
__global__ __launch_bounds__(256) void ln_fused(
    const float* __restrict__ A, const float* __restrict__ R1,
    const float* __restrict__ R2,
    const float* __restrict__ g, const float* __restrict__ be,
    float* __restrict__ out, bf16* __restrict__ outb, float alpha) {
  int row = blockIdx.x, tid = threadIdx.x;
  const float* a  = A  + (size_t)row * D_;
  const float* r1 = R1 + (size_t)row * D_;
  const float* r2 = R2 + (size_t)row * D_;
  float v[3];
  float s = 0.f, s2 = 0.f;
#pragma unroll
  for (int j = 0; j < 3; j++) {
    int col = tid + j * 256;
    float x = a[col] * alpha + r1[col] + r2[col];
    v[j] = x; s += x; s2 += x * x;
  }
  __shared__ float red[8];
#pragma unroll
  for (int off = 32; off >= 1; off >>= 1) {
    s  += __shfl_down(s, off);
    s2 += __shfl_down(s2, off);
  }
  int wv = tid >> 6;
  if ((tid & 63) == 0) { red[wv] = s; red[4 + wv] = s2; }
  __syncthreads();
  s  = red[0] + red[1] + red[2] + red[3];
  s2 = red[4] + red[5] + red[6] + red[7];
  float mu  = s * (1.f / 768.f);
  float var = s2 * (1.f / 768.f) - mu * mu;
  float inv = rsqrtf(var + 1e-5f);
#pragma unroll
  for (int j = 0; j < 3; j++) {
    int col = tid + j * 256;
    float y = (v[j] - mu) * inv * g[col] + be[col];
    out[(size_t)row * D_ + col] = y;
    if (outb) outb[(size_t)row * D_ + col] = (bf16)y;
  }
}

// ---------------------------------------------------------------------------
extern "C" void kernel_launch(void* const* d_in, const int* in_sizes, int n_in,
                              void* d_out, int out_size, void* d_ws, size_t ws_size,
                              hipStream_t stream) {
  const float* states = (const float*)d_in[0];
  const float* pbias  = (const float*)d_in[1];
  const float* Wq = (const float*)d_in[2];
  const float* bq = (const float*)d_in[3];
  const float* Wk = (const float*)d_in[4];
  const float* bk = (const float*)d_in[5];
  const float* Wv = (const float*)d_in[6];
  const float* bv = (const float*)d_in[7];
  const float* Wo = (const float*)d_in[8];
  const float* bo = (const float*)d_in[9];
  const float* grep_w = (const float*)d_in[10];
  const float* grep_b = (const float*)d_in[11];
  const float* grep_a = (const float*)d_in[12];
  const float* ln1_g = (const float*)d_in[13];
  const float* ln1_b = (const float*)d_in[14];
  const float* W1 = (const float*)d_in[15];
  const float* b1 = (const float*)d_in[16];
  const float* W2 = (const float*)d_in[17];
  const float* b2 = (const float*)d_in[18];
  const float* ln2_g = (const float*)d_in[19];
  const float* ln2_b = (const float*)d_in[20];

  float* ws = (float*)d_ws;
  float* qh  = ws;                           // fp32 q (gate), 12 MB
  bf16* q_bf = (bf16*)(ws + 3145728);        // 6 MB  (old kh region, 1st half)
  bf16* k_bf = (bf16*)(ws + 3145728 + 1572864); // 6 MB (old kh region, 2nd half)
  bf16* v_bf = (bf16*)(ws + 6291456);        // 6 MB  (old vh region, 1st half)
  bf16* states_bf = (bf16*)(ws + 9486336);
  bf16* ctx_bf    = (bf16*)(ws + 11059200);
  bf16* x_bf      = (bf16*)(ws + 12632064);
  bf16* h1_bf     = (bf16*)(ws + 14204928);
  bf16* wq_bf     = (bf16*)(ws + 20496384);
  bf16* wk_bf     = (bf16*)(ws + 20791296);
  bf16* wv_bf     = (bf16*)(ws + 21086208);
  bf16* wo_bf     = (bf16*)(ws + 21381120);
  bf16* w1_bf     = (bf16*)(ws + 21676032);
  bf16* w2_bf     = (bf16*)(ws + 22855680);
  // reuse after flash: qh dead (gate done), q_bf/k_bf dead, v_bf dead
  float* attn_a = qh;                 // Wo partial z=0
  float* attn_b = ws + 3145728;       // Wo partial z=1 (over q_bf/k_bf)
  float* x      = ws + 6291456;       // ln1 out (over v_bf)
  float* h2_a   = qh;                 // W2 partial z=0
  float* h2_b   = ws + 3145728;       // W2 partial z=1
  float* outp = (float*)d_out;

  dim3 blk(256);
  cast_all<<<9984, blk, 0, stream>>>(
      (const float4*)states, (const float4*)Wq, (const float4*)Wk,
      (const float4*)Wv, (const float4*)Wo, (const float4*)W1,
      (const float4*)W2,
      (v4bf*)states_bf, (v4bf*)wq_bf, (v4bf*)wk_bf, (v4bf*)wv_bf,
      (v4bf*)wo_bf, (v4bf*)w1_bf, (v4bf*)w2_bf);

  // fused QKV (MFMA): qh fp32 + fragment-tiled bf16 q/k/v
  qkv_mfma<<<dim3(18, 32), blk, 0, stream>>>(states_bf, wq_bf, wk_bf, wv_bf,
                                             bq, bk, bv,
                                             qh, q_bf, k_bf, v_bf);
  // MFMA flash attention (gate inline, bias pass-through fused)
  flash_attn<<<dim3(16, 48), blk, 0, stream>>>(qh, q_bf, k_bf, v_bf, pbias,
                                               grep_w, grep_b, grep_a,
                                               ctx_bf, outp + 3145728);
  // output projection (MFMA, split-K=2)
  gemm_splitk<<<dim3(6, 32, 2), blk, 0, stream>>>(ctx_bf, wo_bf, bo,
                                                  attn_a, attn_b, 768, 768);
  ln_fused<<<4096, blk, 0, stream>>>(states, attn_a, attn_b, ln1_g, ln1_b,
                                     x, x_bf, ALPHA_);
  gemm_mfma<<<dim3(24, 32), blk, 0, stream>>>(x_bf, w1_bf, b1, h1_bf, 768, 3072, MODE_GELU);
  gemm_splitk<<<dim3(6, 32, 2), blk, 0, stream>>>(h1_bf, w2_bf, b2,
                                                  h2_a, h2_b, 3072, 768);
  ln_fused<<<4096, blk, 0, stream>>>(x, h2_a, h2_b, ln2_g, ln2_b,
                                     outp, (bf16*)nullptr, ALPHA_);
}

// Round 14
// 706.116 us; speedup vs baseline: 1.3473x; 1.2560x over previous
//
#include <hip/hip_runtime.h>
#include <hip/hip_bf16.h>

// Problem constants
#define T_    1024
#define B_    4
#define D_    768
#define H_    12
#define HD_   64
#define FF_   3072

typedef __bf16 bf16;
typedef __bf16 v8bf __attribute__((ext_vector_type(8)));
typedef __bf16 v4bf __attribute__((ext_vector_type(4)));
typedef float  v4f  __attribute__((ext_vector_type(4)));

#define AS1 __attribute__((address_space(1)))
#define AS3 __attribute__((address_space(3)))
// async global->LDS, 16B per lane, deposit = wave-uniform base + lane*16
#define GLOAD_LDS(g, l) __builtin_amdgcn_global_load_lds((AS1 void*)(g), (AS3 void*)(l), 16, 0, 0)

static const float ALPHA_ = 2.2133638394006434f; // 24^0.25

#define MODE_PLAIN 0
#define MODE_GELU  1

// ---------------------------------------------------------------------------
// Fused fp32 -> bf16 cast for ALL tensors in one launch.
// ---------------------------------------------------------------------------
#define SEG0 786432            // states end
#define SEG1 (SEG0 + 147456)   // Wq end
#define SEG2 (SEG1 + 147456)   // Wk end
#define SEG3 (SEG2 + 147456)   // Wv end
#define SEG4 (SEG3 + 147456)   // Wo end
#define SEG5 (SEG4 + 589824)   // W1 end
#define SEG6 (SEG5 + 589824)   // W2 end (= 2555904)

__global__ __launch_bounds__(256) void cast_all(
    const float4* __restrict__ states, const float4* __restrict__ wq,
    const float4* __restrict__ wk, const float4* __restrict__ wv,
    const float4* __restrict__ wo, const float4* __restrict__ w1,
    const float4* __restrict__ w2,
    v4bf* __restrict__ o_states, v4bf* __restrict__ o_wq,
    v4bf* __restrict__ o_wk, v4bf* __restrict__ o_wv,
    v4bf* __restrict__ o_wo, v4bf* __restrict__ o_w1,
    v4bf* __restrict__ o_w2) {
  int i = blockIdx.x * 256 + threadIdx.x;
  const float4* src; v4bf* dst; int off;
  if      (i < SEG0) { src = states; dst = o_states; off = 0;    }
  else if (i < SEG1) { src = wq;     dst = o_wq;     off = SEG0; }
  else if (i < SEG2) { src = wk;     dst = o_wk;     off = SEG1; }
  else if (i < SEG3) { src = wv;     dst = o_wv;     off = SEG2; }
  else if (i < SEG4) { src = wo;     dst = o_wo;     off = SEG3; }
  else if (i < SEG5) { src = w1;     dst = o_w1;     off = SEG4; }
  else               { src = w2;     dst = o_w2;     off = SEG5; }
  float4 v = src[i - off];
  v4bf o;
  o[0] = (bf16)v.x; o[1] = (bf16)v.y; o[2] = (bf16)v.z; o[3] = (bf16)v.w;
  dst[i - off] = o;
}

// ---------------------------------------------------------------------------
// MFMA GEMM core (verified): Out(128x128) = X(NxK) @ W(MxK)^T over [kBeg,kEnd).
// ---------------------------------------------------------------------------
__device__ __forceinline__ void gemm_core(
    const bf16* __restrict__ X, const bf16* __restrict__ W, int K,
    int kBeg, int kEnd,
    int row0, int col0, bf16* As, bf16* Bs, v4f (&acc)[4][4]) {
  const int tid  = threadIdx.x;
  const int lane = tid & 63;
  const int w    = tid >> 6;        // wave 0..3
  const int wm   = w >> 1, wn = w & 1;
  const int lr   = lane & 15;       // row within 16-row group
  const int lq   = lane >> 4;       // k-quad 0..3 (8 bf16 = 16B each)

  const bf16* xg0 = X + (size_t)(row0 + 16 * w       + lr) * K + lq * 8;
  const bf16* xg1 = X + (size_t)(row0 + 16 * (w + 4) + lr) * K + lq * 8;
  const bf16* wg0 = W + (size_t)(col0 + 16 * w       + lr) * K + lq * 8;
  const bf16* wg1 = W + (size_t)(col0 + 16 * (w + 4) + lr) * K + lq * 8;
  char* AsB = (char*)As;
  char* BsB = (char*)Bs;

  for (int k0 = kBeg; k0 < kEnd; k0 += 32) {
    __syncthreads();
    GLOAD_LDS(xg0 + k0, AsB + w * 1024);
    GLOAD_LDS(xg1 + k0, AsB + (w + 4) * 1024);
    GLOAD_LDS(wg0 + k0, BsB + w * 1024);
    GLOAD_LDS(wg1 + k0, BsB + (w + 4) * 1024);
    __syncthreads();

    v8bf af[4], bw[4];
#pragma unroll
    for (int mi = 0; mi < 4; mi++)
      af[mi] = *(const v8bf*)(AsB + (wm * 4 + mi) * 1024 + lane * 16);
#pragma unroll
    for (int ni = 0; ni < 4; ni++)
      bw[ni] = *(const v8bf*)(BsB + (wn * 4 + ni) * 1024 + lane * 16);
#pragma unroll
    for (int mi = 0; mi < 4; mi++)
#pragma unroll
      for (int ni = 0; ni < 4; ni++)
        acc[mi][ni] = __builtin_amdgcn_mfma_f32_16x16x32_bf16(
            af[mi], bw[ni], acc[mi][ni], 0, 0, 0);
  }
}

// ---------------------------------------------------------------------------
// Generic MFMA GEMM: out = X @ W^T + bias, PLAIN(f32) or GELU(bf16) epilogue.
// ---------------------------------------------------------------------------
__global__ __launch_bounds__(256) void gemm_mfma(
    const bf16* __restrict__ X, const bf16* __restrict__ W,
    const float* __restrict__ bias, void* __restrict__ out,
    int K, int M, int mode) {
  __shared__ __align__(16) bf16 As[128 * 32];
  __shared__ __align__(16) bf16 Bs[128 * 32];
  const int row0 = blockIdx.y * 128, col0 = blockIdx.x * 128;

  v4f acc[4][4];
  v4f z4 = {0.f, 0.f, 0.f, 0.f};
#pragma unroll
  for (int mi = 0; mi < 4; mi++)
#pragma unroll
    for (int ni = 0; ni < 4; ni++) acc[mi][ni] = z4;

  gemm_core(X, W, K, 0, K, row0, col0, As, Bs, acc);

  const int lane = threadIdx.x & 63;
  const int w = threadIdx.x >> 6, wm = w >> 1, wn = w & 1;
  const int lr = lane & 15, lq = lane >> 4;
#pragma unroll
  for (int ni = 0; ni < 4; ni++) {
    int col = col0 + wn * 64 + ni * 16 + lr;
    float bv = bias[col];
#pragma unroll
    for (int mi = 0; mi < 4; mi++) {
#pragma unroll
      for (int i = 0; i < 4; i++) {
        int row = row0 + wm * 64 + mi * 16 + lq * 4 + i;
        float v = acc[mi][ni][i] + bv;
        if (mode == MODE_GELU) {
          v = 0.5f * v * (1.f + erff(v * 0.70710678118654752f));
          ((bf16*)out)[(size_t)row * M + col] = (bf16)v;
        } else {
          ((float*)out)[(size_t)row * M + col] = v;
        }
      }
    }
  }
}

// ---------------------------------------------------------------------------
// Split-K=2 MFMA GEMM for the under-filled 768-col GEMMs (Wo, W2).
// ---------------------------------------------------------------------------
__global__ __launch_bounds__(256) void gemm_splitk(
    const bf16* __restrict__ X, const bf16* __restrict__ W,
    const float* __restrict__ bias,
    float* __restrict__ out0, float* __restrict__ out1, int K, int M) {
  __shared__ __align__(16) bf16 As[128 * 32];
  __shared__ __align__(16) bf16 Bs[128 * 32];
  const int row0 = blockIdx.y * 128, col0 = blockIdx.x * 128;
  const int z = blockIdx.z;
  const int kh = K >> 1;
  float* outp = z ? out1 : out0;

  v4f acc[4][4];
  v4f z4 = {0.f, 0.f, 0.f, 0.f};
#pragma unroll
  for (int mi = 0; mi < 4; mi++)
#pragma unroll
    for (int ni = 0; ni < 4; ni++) acc[mi][ni] = z4;

  gemm_core(X, W, K, z * kh, z * kh + kh, row0, col0, As, Bs, acc);

  const int lane = threadIdx.x & 63;
  const int w = threadIdx.x >> 6, wm = w >> 1, wn = w & 1;
  const int lr = lane & 15, lq = lane >> 4;
#pragma unroll
  for (int ni = 0; ni < 4; ni++) {
    int col = col0 + wn * 64 + ni * 16 + lr;
    float bv = z ? 0.f : bias[col];
#pragma unroll
    for (int mi = 0; mi < 4; mi++) {
#pragma unroll
      for (int i = 0; i < 4; i++) {
        int row = row0 + wm * 64 + mi * 16 + lq * 4 + i;
        outp[(size_t)row * M + col] = acc[mi][ni][i] + bv;
      }
    }
  }
}

// ---------------------------------------------------------------------------
// Fused QKV MFMA GEMM.  q: writes qh fp32 (for gate) AND q_bf (fragment-tiled
// bf16).  k/v: write ONLY fragment-tiled bf16 (k_bf / v_bf) for MFMA flash.
// Tiled layouts (per head n):
//   q/k:  block = ((n*64 + (t>>4))*2 + (hd>>5)); within-block lane
//         l = (t&15) | (((hd>>3)&3)<<4), j = hd&7  -> A/B fragment order.
//   v^T:  block = ((n*32 + (t>>5))*4 + (hd>>4)); lane
//         l = (hd&15) | (((t>>3)&3)<<4), j = t&7   -> B fragment of V^T.
// ---------------------------------------------------------------------------
__global__ __launch_bounds__(256) void qkv_mfma(
    const bf16* __restrict__ Xb,
    const bf16* __restrict__ Wqb, const bf16* __restrict__ Wkb,
    const bf16* __restrict__ Wvb,
    const float* __restrict__ bq, const float* __restrict__ bk,
    const float* __restrict__ bv,
    float* __restrict__ qh, bf16* __restrict__ qbf,
    bf16* __restrict__ kbf, bf16* __restrict__ vbf) {
  __shared__ __align__(16) bf16 As[128 * 32];
  __shared__ __align__(16) bf16 Bs[128 * 32];
  const int third = blockIdx.x / 6;
  const int xt    = blockIdx.x % 6;
  const bf16*  W    = third == 0 ? Wqb : (third == 1 ? Wkb : Wvb);
  const float* bias = third == 0 ? bq  : (third == 1 ? bk  : bv);
  const int row0 = blockIdx.y * 128, col0 = xt * 128;

  v4f acc[4][4];
  v4f z4 = {0.f, 0.f, 0.f, 0.f};
#pragma unroll
  for (int mi = 0; mi < 4; mi++)
#pragma unroll
    for (int ni = 0; ni < 4; ni++) acc[mi][ni] = z4;

  gemm_core(Xb, W, D_, 0, D_, row0, col0, As, Bs, acc);

  const int lane = threadIdx.x & 63;
  const int w = threadIdx.x >> 6, wm = w >> 1, wn = w & 1;
  const int lr = lane & 15, lq = lane >> 4;
#pragma unroll
  for (int ni = 0; ni < 4; ni++) {
    int col = col0 + wn * 64 + ni * 16 + lr;
    float bvv = bias[col];
    int h = col >> 6, hd = col & 63;
#pragma unroll
    for (int mi = 0; mi < 4; mi++) {
#pragma unroll
      for (int i = 0; i < 4; i++) {
        int row = row0 + wm * 64 + mi * 16 + lq * 4 + i; // token = t*B + bb
        int t = row >> 2, bb = row & 3;
        int n2 = bb * H_ + h;
        float v = acc[mi][ni][i] + bvv;
        if (third == 0) {
          v *= (0.125f / 32.f);
          qh[(((size_t)n2) * T_ + t) * HD_ + hd] = v;
          size_t idx = (((size_t)n2 * 64 + (t >> 4)) * 2 + (hd >> 5)) * 512
                     + (((t & 15) | (((hd >> 3) & 3) << 4)) << 3) + (hd & 7);
          qbf[idx] = (bf16)v;
        } else if (third == 1) {
          size_t idx = (((size_t)n2 * 64 + (t >> 4)) * 2 + (hd >> 5)) * 512
                     + (((t & 15) | (((hd >> 3) & 3) << 4)) << 3) + (hd & 7);
          kbf[idx] = (bf16)v;
        } else {
          size_t idx = (((size_t)n2 * 32 + (t >> 5)) * 4 + (hd >> 4)) * 512
                     + (((hd & 15) | (((t >> 3) & 3) << 4)) << 3) + (t & 7);
          vbf[idx] = (bf16)v;
        }
      }
    }
  }
}

// ---------------------------------------------------------------------------
// MFMA flash attention, BARRIER-FREE.  Per block: head n, 64 q-rows, 4 waves
// x 16 rows, fully independent (no __syncthreads, no shared bias tile).
//  - bias pass-through: per-thread register prefetch stream, PLAIN v4f
//    loads/stores (populate L2 / write-combine; NT caused 2.25x write ampl).
//  - softmax bias values read directly from global in C-fragment order;
//    they hit L2 because the copy stream loaded those lines one tile earlier.
//  - V fragments loaded before softmax so their latency hides under exp.
//  - only LDS: per-wave 2KB P buffer (wave-private, in-order DS, no barrier).
// ---------------------------------------------------------------------------
__global__ __launch_bounds__(256) void flash_attn(
    const float* __restrict__ Q, const bf16* __restrict__ Qt,
    const bf16* __restrict__ Kt, const bf16* __restrict__ Vt,
    const float* __restrict__ bias,
    const float* __restrict__ grep_w, const float* __restrict__ grep_b,
    const float* __restrict__ grep_a,
    bf16* __restrict__ ctx, float* __restrict__ bias_out) {
  __shared__ __align__(16) bf16 Pbuf[4][1024];
  const int n  = blockIdx.y;
  const int R0 = blockIdx.x * 64;
  const int tid = threadIdx.x;
  const int l  = tid & 63, w = tid >> 6;
  const int lo = l & 15, hi = l >> 4;
  const int b = n / H_, h = n % H_;

  // ---- gate for this wave's 16 rows (row = R0+16w+lo, d-slice hi*16..+15)
  float ms;
  {
    const float* qrow = Q + (((size_t)n * T_ + R0 + 16 * w + lo)) * HD_ + hi * 16;
    float4 qa = *(const float4*)qrow;
    float4 qb2 = *(const float4*)(qrow + 4);
    float4 qc = *(const float4*)(qrow + 8);
    float4 qd = *(const float4*)(qrow + 12);
    float qv[16] = {qa.x, qa.y, qa.z, qa.w, qb2.x, qb2.y, qb2.z, qb2.w,
                    qc.x, qc.y, qc.z, qc.w, qd.x, qd.y, qd.z, qd.w};
    float z[8];
#pragma unroll
    for (int o = 0; o < 8; o++) {
      const float* gw = grep_w + o * 64 + hi * 16;
      float a = 0.f;
#pragma unroll
      for (int j = 0; j < 16; j++) a += qv[j] * gw[j];
      z[o] = a;
    }
#pragma unroll
    for (int o = 0; o < 8; o++) {
      z[o] += __shfl_xor(z[o], 16);
      z[o] += __shfl_xor(z[o], 32);
    }
    float gb03 = grep_b[0] + grep_b[1] + grep_b[2] + grep_b[3];
    float gb47 = grep_b[4] + grep_b[5] + grep_b[6] + grep_b[7];
    float s0 = (z[0] + z[1] + z[2] + z[3]) * 256.f + gb03;
    float s1 = (z[4] + z[5] + z[6] + z[7]) * 256.f + gb47;
    float ga = 1.f / (1.f + __expf(-s0));
    float gbv = 1.f / (1.f + __expf(-s1));
    ms = ga * (gbv * grep_a[h] - 1.f) + 2.f;
  }
  // redistribute: reg-row i needs ms of row hi*4+i (held at lane hi*4+i)
  float ms_row[4];
#pragma unroll
  for (int i = 0; i < 4; i++) ms_row[i] = __shfl(ms, hi * 4 + i);

  // ---- Q fragments (persistent): lane l -> Q[16w + (l&15)][32q + (l>>4)*8+j]
  v8bf qf[2];
  {
    const bf16* qb = Qt + (((size_t)n * 64 + (R0 >> 4) + w) * 2) * 512 + (size_t)l * 8;
    qf[0] = *(const v8bf*)qb;
    qf[1] = *(const v8bf*)(qb + 512);
  }

  float m_[4], l_[4];
  v4f acc[4];
  v4f zz = {0.f, 0.f, 0.f, 0.f};
#pragma unroll
  for (int i = 0; i < 4; i++) { m_[i] = -1e30f; l_[i] = 0.f; acc[i] = zz; }

  // ---- bias copy stream (plain loads/stores; row tid>>2, cols (tid&3)*16+..)
  const int brow = tid >> 2, bc = (tid & 3) * 16;
  const float* bg = bias + ((size_t)n * T_ + R0 + brow) * T_ + bc;
  float* bo = bias_out + ((size_t)n * T_ + R0 + brow) * T_ + bc;
  v4f br4[4];
#pragma unroll
  for (int k = 0; k < 4; k++) br4[k] = *(const v4f*)(bg + k * 4);

  // ---- bias compute-read base: row i of this lane at bcr0 + i*T_ + col
  const float* bcr0 = bias + ((size_t)n * T_ + R0 + 16 * w + hi * 4) * T_ + lo;

  for (int cb = 0; cb < T_; cb += 64) {
    // 1. bias compute reads (C-layout), L2-warm from copy stream
    float bw_[4][4];
#pragma unroll
    for (int ct = 0; ct < 4; ct++)
#pragma unroll
      for (int i = 0; i < 4; i++)
        bw_[ct][i] = bcr0[(size_t)i * T_ + cb + ct * 16];

    // 2. K fragment loads (all 8 up front)
    const bf16* kb = Kt + (((size_t)n * 64 + (cb >> 4)) * 2) * 512 + (size_t)l * 8;
    v8bf kf[8];
#pragma unroll
    for (int ct = 0; ct < 4; ct++) {
      kf[2 * ct]     = *(const v8bf*)(kb + ct * 1024);
      kf[2 * ct + 1] = *(const v8bf*)(kb + ct * 1024 + 512);
    }

    // 3. copy stream: store tile cb, prefetch tile cb+64
#pragma unroll
    for (int k = 0; k < 4; k++) *(v4f*)(bo + cb + k * 4) = br4[k];
    if (cb + 64 < T_) {
#pragma unroll
      for (int k = 0; k < 4; k++)
        br4[k] = *(const v4f*)(bg + cb + 64 + k * 4);
    }

    // 4. QK^T MFMAs
    v4f sc[4];
#pragma unroll
    for (int ct = 0; ct < 4; ct++) {
      v4f s = zz;
      s = __builtin_amdgcn_mfma_f32_16x16x32_bf16(qf[0], kf[2 * ct], s, 0, 0, 0);
      s = __builtin_amdgcn_mfma_f32_16x16x32_bf16(qf[1], kf[2 * ct + 1], s, 0, 0, 0);
      sc[ct] = s;
    }

    // 5. V fragment loads (issued before softmax to hide latency under exp)
    const bf16* vb = Vt + (((size_t)n * 32 + (cb >> 5)) * 4) * 512 + (size_t)l * 8;
    v8bf vf[8];
#pragma unroll
    for (int dt = 0; dt < 4; dt++) {
      vf[2 * dt]     = *(const v8bf*)(vb + dt * 512);
      vf[2 * dt + 1] = *(const v8bf*)(vb + (dt + 4) * 512);
    }

    // 6. softmax (C-layout), online max/sum per reg-row
    float vals[4][4];
    float tm[4] = {-1e30f, -1e30f, -1e30f, -1e30f};
#pragma unroll
    for (int ct = 0; ct < 4; ct++)
#pragma unroll
      for (int i = 0; i < 4; i++) {
        float vv = sc[ct][i] * 32.f + ms_row[i] * bw_[ct][i];
        vals[ct][i] = vv;
        tm[i] = fmaxf(tm[i], vv);
      }
#pragma unroll
    for (int i = 0; i < 4; i++) {
      tm[i] = fmaxf(tm[i], __shfl_xor(tm[i], 1));
      tm[i] = fmaxf(tm[i], __shfl_xor(tm[i], 2));
      tm[i] = fmaxf(tm[i], __shfl_xor(tm[i], 4));
      tm[i] = fmaxf(tm[i], __shfl_xor(tm[i], 8));
    }
    float al[4], ls[4];
#pragma unroll
    for (int i = 0; i < 4; i++) {
      float mn = fmaxf(m_[i], tm[i]);
      al[i] = __expf(m_[i] - mn);
      m_[i] = mn;
      ls[i] = 0.f;
    }
#pragma unroll
    for (int ct = 0; ct < 4; ct++)
#pragma unroll
      for (int i = 0; i < 4; i++) {
        float p = __expf(vals[ct][i] - m_[i]);
        ls[i] += p;
        int sg = ct * 16 + lo;   // local kv col 0..63
        int idx = (sg >> 5) * 512
                + (((hi * 4 + i) | (((sg >> 3) & 3) << 4)) << 3) + (sg & 7);
        Pbuf[w][idx] = (bf16)p;
      }
#pragma unroll
    for (int i = 0; i < 4; i++) {
      ls[i] += __shfl_xor(ls[i], 1);
      ls[i] += __shfl_xor(ls[i], 2);
      ls[i] += __shfl_xor(ls[i], 4);
      ls[i] += __shfl_xor(ls[i], 8);
      l_[i] = l_[i] * al[i] + ls[i];
    }
#pragma unroll
    for (int dt = 0; dt < 4; dt++)
#pragma unroll
      for (int i = 0; i < 4; i++) acc[dt][i] *= al[i];

    // 7. PV: lane-indexed A-fragment read of P, MFMA vs preloaded V frags
    v8bf pf0 = *(const v8bf*)&Pbuf[w][(size_t)l * 8];
    v8bf pf1 = *(const v8bf*)&Pbuf[w][512 + (size_t)l * 8];
#pragma unroll
    for (int dt = 0; dt < 4; dt++) {
      acc[dt] = __builtin_amdgcn_mfma_f32_16x16x32_bf16(pf0, vf[2 * dt], acc[dt], 0, 0, 0);
      acc[dt] = __builtin_amdgcn_mfma_f32_16x16x32_bf16(pf1, vf[2 * dt + 1], acc[dt], 0, 0, 0);
    }
  }

  float inv[4];
#pragma unroll
  for (int i = 0; i < 4; i++) inv[i] = 1.f / l_[i];
#pragma unroll
  for (int dt = 0; dt < 4; dt++)
#pragma unroll
    for (int i = 0; i < 4; i++) {
      int t0 = R0 + 16 * w + hi * 4 + i;
      ctx[((size_t)(t0 * B_ + b)) * D_ + h * HD_ + dt * 16 + lo] =
          (bf16)(acc[dt][i] * inv[i]);
    }
}

// ---------------------------------------------------------------------------
// Fused residual + LayerNorm with split-K partial merge.
// ---------------------------------------------------------------------------
__global__ __launch_bounds__(256) void ln_fused(
    const float* __restrict__ A, const float* __restrict__ R1,
    const float* __restrict__ R2,
    const float* __restrict__ g, const float* __restrict__ be,
    float* __restrict__ out, bf16* __restrict__ outb, float alpha) {
  int row = blockIdx.x, tid = threadIdx.x;
  const float* a  = A  + (size_t)row * D_;
  const float* r1 = R1 + (size_t)row * D_;
  const float* r2 = R2 + (size_t)row * D_;
  float v[3];
  float s = 0.f, s2 = 0.f;
#pragma unroll
  for (int j = 0; j < 3; j++) {
    int col = tid + j * 256;
    float x = a[col] * alpha + r1[col] + r2[col];
    v[j] = x; s += x; s2 += x * x;
  }
  __shared__ float red[8];
#pragma unroll
  for (int off = 32; off >= 1; off >>= 1) {
    s  += __shfl_down(s, off);
    s2 += __shfl_down(s2, off);
  }
  int wv = tid >> 6;
  if ((tid & 63) == 0) { red[wv] = s; red[4 + wv] = s2; }
  __syncthreads();
  s  = red[0] + red[1] + red[2] + red[3];
  s2 = red[4] + red[5] + red[6] + red[7];
  float mu  = s * (1.f / 768.f);
  float var = s2 * (1.f / 768.f) - mu * mu;
  float inv = rsqrtf(var + 1e-5f);
#pragma unroll
  for (int j = 0; j < 3; j++) {
    int col = tid + j * 256;
    float y = (v[j] - mu) * inv * g[col] + be[col];
    out[(size_t)row * D_ + col] = y;
    if (outb) outb[(size_t)row * D_ + col] = (bf16)y;
  }
}

// ---------------------------------------------------------------------------
extern "C" void kernel_launch(void* const* d_in, const int* in_sizes, int n_in,
                              void* d_out, int out_size, void* d_ws, size_t ws_size,
                              hipStream_t stream) {
  const float* states = (const float*)d_in[0];
  const float* pbias  = (const float*)d_in[1];
  const float* Wq = (const float*)d_in[2];
  const float* bq = (const float*)d_in[3];
  const float* Wk = (const float*)d_in[4];
  const float* bk = (const float*)d_in[5];
  const float* Wv = (const float*)d_in[6];
  const float* bv = (const float*)d_in[7];
  const float* Wo = (const float*)d_in[8];
  const float* bo = (const float*)d_in[9];
  const float* grep_w = (const float*)d_in[10];
  const float* grep_b = (const float*)d_in[11];
  const float* grep_a = (const float*)d_in[12];
  const float* ln1_g = (const float*)d_in[13];
  const float* ln1_b = (const float*)d_in[14];
  const float* W1 = (const float*)d_in[15];
  const float* b1 = (const float*)d_in[16];
  const float* W2 = (const float*)d_in[17];
  const float* b2 = (const float*)d_in[18];
  const float* ln2_g = (const float*)d_in[19];
  const float* ln2_b = (const float*)d_in[20];

  float* ws = (float*)d_ws;
  float* qh  = ws;                           // fp32 q (gate), 12 MB
  bf16* q_bf = (bf16*)(ws + 3145728);        // 6 MB  (old kh region, 1st half)
  bf16* k_bf = (bf16*)(ws + 3145728 + 1572864); // 6 MB (old kh region, 2nd half)
  bf16* v_bf = (bf16*)(ws + 6291456);        // 6 MB  (old vh region, 1st half)
  bf16* states_bf = (bf16*)(ws + 9486336);
  bf16* ctx_bf    = (bf16*)(ws + 11059200);
  bf16* x_bf      = (bf16*)(ws + 12632064);
  bf16* h1_bf     = (bf16*)(ws + 14204928);
  bf16* wq_bf     = (bf16*)(ws + 20496384);
  bf16* wk_bf     = (bf16*)(ws + 20791296);
  bf16* wv_bf     = (bf16*)(ws + 21086208);
  bf16* wo_bf     = (bf16*)(ws + 21381120);
  bf16* w1_bf     = (bf16*)(ws + 21676032);
  bf16* w2_bf     = (bf16*)(ws + 22855680);
  // reuse after flash: qh dead (gate done), q_bf/k_bf dead, v_bf dead
  float* attn_a = qh;                 // Wo partial z=0
  float* attn_b = ws + 3145728;       // Wo partial z=1 (over q_bf/k_bf)
  float* x      = ws + 6291456;       // ln1 out (over v_bf)
  float* h2_a   = qh;                 // W2 partial z=0
  float* h2_b   = ws + 3145728;       // W2 partial z=1
  float* outp = (float*)d_out;

  dim3 blk(256);
  cast_all<<<9984, blk, 0, stream>>>(
      (const float4*)states, (const float4*)Wq, (const float4*)Wk,
      (const float4*)Wv, (const float4*)Wo, (const float4*)W1,
      (const float4*)W2,
      (v4bf*)states_bf, (v4bf*)wq_bf, (v4bf*)wk_bf, (v4bf*)wv_bf,
      (v4bf*)wo_bf, (v4bf*)w1_bf, (v4bf*)w2_bf);

  // fused QKV (MFMA): qh fp32 + fragment-tiled bf16 q/k/v
  qkv_mfma<<<dim3(18, 32), blk, 0, stream>>>(states_bf, wq_bf, wk_bf, wv_bf,
                                             bq, bk, bv,
                                             qh, q_bf, k_bf, v_bf);
  // MFMA flash attention (barrier-free; gate inline, bias pass-through fused)
  flash_attn<<<dim3(16, 48), blk, 0, stream>>>(qh, q_bf, k_bf, v_bf, pbias,
                                               grep_w, grep_b, grep_a,
                                               ctx_bf, outp + 3145728);
  // output projection (MFMA, split-K=2)
  gemm_splitk<<<dim3(6, 32, 2), blk, 0, stream>>>(ctx_bf, wo_bf, bo,
                                                  attn_a, attn_b, 768, 768);
  ln_fused<<<4096, blk, 0, stream>>>(states, attn_a, attn_b, ln1_g, ln1_b,
                                     x, x_bf, ALPHA_);
  gemm_mfma<<<dim3(24, 32), blk, 0, stream>>>(x_bf, w1_bf, b1, h1_bf, 768, 3072, MODE_GELU);
  gemm_splitk<<<dim3(6, 32, 2), blk, 0, stream>>>(h1_bf, w2_bf, b2,
                                                  h2_a, h2_b, 3072, 768);
  ln_fused<<<4096, blk, 0, stream>>>(x, h2_a, h2_b, ln2_g, ln2_b,
                                     outp, (bf16*)nullptr, ALPHA_);
}